// Round 2
// baseline (2536.498 us; speedup 1.0000x reference)
//
#include <hip/hip_runtime.h>
#include <cstddef>

namespace {
constexpr int kBatch = 32, kH = 512, kW = 512, kCin = 6, kCout = 16, kFs = 5;
constexpr int kOH = kH - kFs + 1, kOW = kW - kFs + 1;  // 508
constexpr int kTW = 64, kTH = 32;           // output tile per block
constexpr int kIW = kTW + kFs - 1;          // 68 input cols (halo)
constexpr int kIH = kTH + kFs - 1;          // 36 input rows
constexpr int kPlane = kIH * kIW;           // 2448 floats per channel plane
constexpr int kNP = kFs * kFs * kCin;       // 150 (tap, cin) combos
constexpr int kWA = kNP * 8;                // 1200: first 8 packed weights
constexpr int kWB = kNP * 2;                // 300:  last 2 packed weights
constexpr int kPairsRow = kIW / 2;          // 34 pixel-pairs per row
constexpr int kPairs = kIH * kPairsRow;     // 1224 staging tasks

// Per-input-channel list of the 10 structurally-nonzero output channels
// (validated: round-1 kernel using this table passed the harness check).
__device__ constexpr int kSet[6][10] = {
    {0, 4, 5, 6, 9, 10, 11, 12, 14, 15},
    {0, 1, 5, 6, 7, 10, 11, 12, 13, 15},
    {0, 1, 2, 6, 7, 8, 11, 13, 14, 15},
    {1, 2, 3, 6, 7, 8, 9, 12, 14, 15},
    {2, 3, 4, 7, 8, 9, 10, 12, 13, 15},
    {3, 4, 5, 8, 9, 10, 11, 13, 14, 15},
};
}  // namespace

// Pack the 10 nonzero weights per (tap p, cin c) into wd:
//   wd[0 .. 1199]        = A[pc][j], j = 0..7
//   wd[1200 .. 1499]     = B[pc][j-8], j = 8..9
__global__ void assemble_weights(const float* __restrict__ w3,
                                 const float* __restrict__ w4,
                                 const float* __restrict__ w44,
                                 const float* __restrict__ w6,
                                 float* __restrict__ wd) {
  int i = blockIdx.x * blockDim.x + threadIdx.x;
  if (i >= kNP * 10) return;
  int j = i % 10;
  int pc = i / 10;          // p*6 + c
  int c = pc % kCin;
  int p = pc / kCin;        // ky*5 + kx
  int o = kSet[c][j];
  float val = 0.f;
  if (o < 6) {
    int m = (c - o + 6) % 6;
    if (m < 3) val = w3[(p * 3 + m) * 6 + o];
  } else if (o < 12) {
    int k = o - 6;
    int m = (c - k + 6) % 6;
    if (m < 4) val = w4[(p * 4 + m) * 6 + k];
  } else if (o < 15) {
    int k = o - 12;
    int d = (c - k + 6) % 6;
    int m = (d == 0) ? 0 : (d == 1) ? 1 : (d == 3) ? 2 : (d == 4) ? 3 : -1;
    if (m >= 0) val = w44[(p * 4 + m) * 3 + k];
  } else {
    val = w6[p * 6 + c];
  }
  if (j < 8) wd[pc * 8 + j] = val;
  else       wd[kWA + pc * 2 + (j - 8)] = val;
}

__global__ __launch_bounds__(256, 2) void conv_sparse(
    const float* __restrict__ in, const float* __restrict__ wd,
    const float* __restrict__ bias, float* __restrict__ out) {
  // Channel-planar input tile + sparse-packed weights. 64752 B total (<64 KB).
  __shared__ float s_in[kCin * kPlane];  // 6*2448 = 14688 floats
  __shared__ float s_wa[kWA];            // 1200 floats
  __shared__ float s_wb[kWB];            // 300 floats

  const int t = threadIdx.x;
  const int x0 = blockIdx.x * kTW, y0 = blockIdx.y * kTH;
  const int b = blockIdx.z;

  for (int i = t; i < kWA; i += 256) s_wa[i] = wd[i];
  for (int i = t; i < kWB; i += 256) s_wb[i] = wd[kWA + i];

  // Stage input tile, transposing NHWC (c-interleaved) -> channel-planar.
  // Each task: 2 consecutive pixels = 12 floats = 3 float4 global loads,
  // scattered as 6 float2 LDS writes (one per plane, 8B-aligned).
  const float* inb = in + (size_t)b * kH * kW * kCin;
  const bool interior = (x0 + kIW <= kW) && (y0 + kIH <= kH);
  if (interior) {
    for (int i = t; i < kPairs; i += 256) {
      int r = i / kPairsRow, pr = i - r * kPairsRow;
      const float4* g =
          (const float4*)(inb + ((size_t)(y0 + r) * kW + x0 + pr * 2) * kCin);
      float4 a = g[0], bq = g[1], cq = g[2];
      int base = r * kIW + pr * 2;
      *(float2*)&s_in[0 * kPlane + base] = make_float2(a.x, bq.z);
      *(float2*)&s_in[1 * kPlane + base] = make_float2(a.y, bq.w);
      *(float2*)&s_in[2 * kPlane + base] = make_float2(a.z, cq.x);
      *(float2*)&s_in[3 * kPlane + base] = make_float2(a.w, cq.y);
      *(float2*)&s_in[4 * kPlane + base] = make_float2(bq.x, cq.z);
      *(float2*)&s_in[5 * kPlane + base] = make_float2(bq.y, cq.w);
    }
  } else {
    for (int i = t; i < kPairs; i += 256) {
      int r = i / kPairsRow, pr = i - r * kPairsRow;
      int gy = y0 + r, gx = x0 + pr * 2;
      float v[12];
#pragma unroll
      for (int k2 = 0; k2 < 12; ++k2) v[k2] = 0.f;
      if (gy < kH) {
        const float* g = inb + ((size_t)gy * kW + gx) * kCin;
        if (gx + 1 < kW) {
#pragma unroll
          for (int k2 = 0; k2 < 12; ++k2) v[k2] = g[k2];
        } else if (gx < kW) {
#pragma unroll
          for (int k2 = 0; k2 < 6; ++k2) v[k2] = g[k2];
        }
      }
      int base = r * kIW + pr * 2;
#pragma unroll
      for (int c = 0; c < kCin; ++c)
        *(float2*)&s_in[c * kPlane + base] = make_float2(v[c], v[6 + c]);
    }
  }
  __syncthreads();

  // Thread -> 8 consecutive x outputs in one row: tx in [0,8), ty in [0,32).
  const int tx = t & 7, ty = t >> 3;
  const int xl = tx * 8;

  float acc[8][16];
#pragma unroll
  for (int o = 0; o < kCout; ++o) {
    const float bo = bias[o];
#pragma unroll
    for (int r = 0; r < 8; ++r) acc[r][o] = bo;
  }

#pragma unroll 1
  for (int ky = 0; ky < kFs; ++ky) {
    const float* prow = &s_in[(ty + ky) * kIW + xl];
#pragma unroll
    for (int c = 0; c < kCin; ++c) {
      // 12 consecutive-x inputs: 3 x ds_read_b128, reused across 5 kx taps.
      const float4* p4 = (const float4*)(prow + c * kPlane);
      const float4 i0 = p4[0], i1 = p4[1], i2 = p4[2];
      const float inv[12] = {i0.x, i0.y, i0.z, i0.w, i1.x, i1.y,
                             i1.z, i1.w, i2.x, i2.y, i2.z, i2.w};
#pragma unroll
      for (int kx = 0; kx < kFs; ++kx) {
        const int pc = (ky * kFs + kx) * kCin + c;
        const float4* wa = (const float4*)&s_wa[pc * 8];
        const float4 w0 = wa[0], w1 = wa[1];
        const float2 wb = *(const float2*)&s_wb[pc * 2];
#pragma unroll
        for (int r = 0; r < 8; ++r) {
          const float v = inv[kx + r];  // static index after unroll
          acc[r][kSet[c][0]] += v * w0.x;
          acc[r][kSet[c][1]] += v * w0.y;
          acc[r][kSet[c][2]] += v * w0.z;
          acc[r][kSet[c][3]] += v * w0.w;
          acc[r][kSet[c][4]] += v * w1.x;
          acc[r][kSet[c][5]] += v * w1.y;
          acc[r][kSet[c][6]] += v * w1.z;
          acc[r][kSet[c][7]] += v * w1.w;
          acc[r][kSet[c][8]] += v * wb.x;
          acc[r][kSet[c][9]] += v * wb.y;
        }
      }
    }
  }

  // Store 8 px * 16 ch, 64B per pixel (512B contiguous per thread).
  const int oy = y0 + ty;
  if (oy < kOH) {
#pragma unroll
    for (int r = 0; r < 8; ++r) {
      const int ox = x0 + xl + r;
      if (ox < kOW) {
        float4* op = (float4*)&out[(((size_t)b * kOH + oy) * kOW + ox) * kCout];
        op[0] = make_float4(acc[r][0], acc[r][1], acc[r][2], acc[r][3]);
        op[1] = make_float4(acc[r][4], acc[r][5], acc[r][6], acc[r][7]);
        op[2] = make_float4(acc[r][8], acc[r][9], acc[r][10], acc[r][11]);
        op[3] = make_float4(acc[r][12], acc[r][13], acc[r][14], acc[r][15]);
      }
    }
  }
}

extern "C" void kernel_launch(void* const* d_in, const int* in_sizes, int n_in,
                              void* d_out, int out_size, void* d_ws, size_t ws_size,
                              hipStream_t stream) {
  const float* in   = (const float*)d_in[0];
  const float* w3   = (const float*)d_in[1];
  const float* w4   = (const float*)d_in[2];
  const float* w44  = (const float*)d_in[3];
  const float* w6   = (const float*)d_in[4];
  const float* bias = (const float*)d_in[5];
  float* out = (float*)d_out;
  float* wd  = (float*)d_ws;  // 1500 floats of packed-weight scratch

  assemble_weights<<<(kNP * 10 + 255) / 256, 256, 0, stream>>>(w3, w4, w44, w6, wd);

  dim3 grid((kOW + kTW - 1) / kTW, (kOH + kTH - 1) / kTH, kBatch);
  conv_sparse<<<grid, 256, 0, stream>>>(in, wd, bias, out);
}